// Round 12
// baseline (401.358 us; speedup 1.0000x reference)
//
#include <hip/hip_runtime.h>
#include <math.h>

// Problem constants
#define Bb 2
#define Ll 2048
#define DMODEL 1024
#define DINNER 2048
#define DSTATE 8
#define DTRANK 64
#define DCONV 4
#define MM (Bb*Ll)          // 4096 rows
// scan chunking (r12: CL 32->64, NCH 64->32 — halves cs traffic + p2 chain)
#define NCH 32
#define CL 64               // NCH*CL == Ll
// G3 split-K
#define G3_KCH 8
#define G3_KC (DINNER / G3_KCH)   // 256

typedef __attribute__((ext_vector_type(8))) short    bf16x8;
typedef __attribute__((ext_vector_type(8))) unsigned short u16x8;
typedef __attribute__((ext_vector_type(4))) float    f32x4;

__device__ __forceinline__ float silu_f(float x) {
    return x / (1.0f + __expf(-x));
}
__device__ __forceinline__ float softplus_f(float x) {
    return fmaxf(x, 0.0f) + log1pf(__expf(-fabsf(x)));
}
__device__ __forceinline__ unsigned short f2bf(float f) {
    unsigned int u = __float_as_uint(f);
    u += 0x7fffu + ((u >> 16) & 1u);      // RNE
    return (unsigned short)(u >> 16);
}
__device__ __forceinline__ float bf2f(unsigned short u) {
    return __uint_as_float(((unsigned int)u) << 16);
}
// async 16B global->LDS (wave-uniform LDS base + lane*16 dest)
__device__ __forceinline__ void async_cp16(const unsigned short* g, unsigned short* l) {
    __builtin_amdgcn_global_load_lds(
        (const __attribute__((address_space(1))) void*)g,
        (__attribute__((address_space(3))) void*)l, 16, 0, 0);
}

// ---------------------------------------------------------------------------
// bf16 MFMA GEMM (r11-proven, untouched): NW waves, tile 128 x TN, BK=32,
// double-buffered async staging, flat LDS + 16B-slot XOR swizzle -> 0 bank
// conflicts. ~650-670 TF structural plateau (1-barrier K-loop, m97-class);
// measured invariant across NW/TN/split-K (r5-r11).
// ---------------------------------------------------------------------------
template <int EPI, int NW, int TN, typename OT>
__global__ __launch_bounds__(NW * 64, 4) void mfma_gemm(
    const unsigned short* __restrict__ A, const unsigned short* __restrict__ Bt,
    OT* __restrict__ C, OT* __restrict__ C2, int nsplit,
    int M, int N, int K, int lda, int ldb, int ldc,
    const float* __restrict__ bias)
{
    constexpr int NT   = NW * 64;
    constexpr int WNC  = NW / 2;
    constexpr int WNE  = TN / WNC;
    constexpr int NJ   = WNE / 16;
    constexpr int RPP  = NT / 4;
    constexpr int APASS = 128 / RPP;
    constexpr int BPASS = TN / RPP;

    __shared__ unsigned short As[2][128 * 32];
    __shared__ unsigned short Bs[2][TN * 32];

    const int bm = blockIdx.y * 128;
    const int bn = blockIdx.x * TN;
    const int tid  = threadIdx.x;
    const int w    = tid >> 6;
    const int lane = tid & 63;
    const int wm = (w / WNC) * 64;
    const int wn = (w % WNC) * WNE;
    const int lr = lane & 15;
    const int lq = lane >> 4;

    const int row  = tid >> 2;
    const int sp   = tid & 3;
    const int slog = sp ^ ((row >> 1) & 3);
    const unsigned short* gA = A  + (size_t)(bm + row) * lda + slog * 8;
    const unsigned short* gB = Bt + (size_t)(bn + row) * ldb + slog * 8;
    const int st = tid * 8;

    const int fsw = (lq ^ ((lr >> 1) & 3)) * 8;

    f32x4 acc[4][NJ];
#pragma unroll
    for (int i = 0; i < 4; ++i)
#pragma unroll
        for (int j = 0; j < NJ; ++j) acc[i][j] = (f32x4){0.f, 0.f, 0.f, 0.f};

#pragma unroll
    for (int p = 0; p < APASS; ++p)
        async_cp16(gA + (size_t)p * RPP * lda, &As[0][p * RPP * 32 + st]);
#pragma unroll
    for (int p = 0; p < BPASS; ++p)
        async_cp16(gB + (size_t)p * RPP * ldb, &Bs[0][p * RPP * 32 + st]);

    int cur = 0;
    for (int k0 = 0; k0 < K; k0 += 32, cur ^= 1) {
        __syncthreads();
        const int nk = k0 + 32;
        if (nk < K) {
            const int nb = cur ^ 1;
#pragma unroll
            for (int p = 0; p < APASS; ++p)
                async_cp16(gA + (size_t)p * RPP * lda + nk, &As[nb][p * RPP * 32 + st]);
#pragma unroll
            for (int p = 0; p < BPASS; ++p)
                async_cp16(gB + (size_t)p * RPP * ldb + nk, &Bs[nb][p * RPP * 32 + st]);
        }

        bf16x8 a[4], b[NJ];
#pragma unroll
        for (int i = 0; i < 4; ++i)
            a[i] = *(const bf16x8*)&As[cur][(wm + i * 16 + lr) * 32 + fsw];
#pragma unroll
        for (int j = 0; j < NJ; ++j)
            b[j] = *(const bf16x8*)&Bs[cur][(wn + j * 16 + lr) * 32 + fsw];
#pragma unroll
        for (int i = 0; i < 4; ++i)
#pragma unroll
            for (int j = 0; j < NJ; ++j)
                acc[i][j] = __builtin_amdgcn_mfma_f32_16x16x32_bf16(
                    a[i], b[j], acc[i][j], 0, 0, 0);
    }

    // epilogue: C/D layout col = lane&15, row = (lane>>4)*4 + reg
#pragma unroll
    for (int i = 0; i < 4; ++i) {
        const int row0 = bm + wm + i * 16 + lq * 4;
#pragma unroll
        for (int j = 0; j < NJ; ++j) {
            const int col = bn + wn + j * 16 + lr;
            OT* Cb; int colb;
            if (col < nsplit) { Cb = C; colb = col; }
            else              { Cb = C2; colb = col - nsplit; }
            float bv = (EPI == 1) ? bias[col] : 0.0f;
#pragma unroll
            for (int r = 0; r < 4; ++r) {
                float v = acc[i][j][r];
                if (EPI == 1) v = silu_f(v + bv);
                if (sizeof(OT) == 2)
                    Cb[(size_t)(row0 + r) * ldc + colb] = (OT)f2bf(v);
                else
                    Cb[(size_t)(row0 + r) * ldc + colb] = (OT)v;
            }
        }
    }
}

// ---------------------------------------------------------------------------
// prep_all (r12: 64x64 transpose tiles, float4 reads / ushort8 writes).
// Block ranges:
//   [0,4096)      cast x -> bf16 (1024 elems/block, float4)
//   [4096,5120)   W_in  [1024][4096] -> Wint  [4096][1024]   (16 x 64 tiles)
//   [5120,6144)   pwk   [2048][2048] -> pw_t  [2048][2048]   (32 x 32 tiles)
//   [6144,6656)   W_out [2048][1024] -> Woutt [1024][2048]   (32 x 16 tiles)
// ---------------------------------------------------------------------------
__global__ __launch_bounds__(256) void prep_all(
    const float* __restrict__ x, const float* __restrict__ W_in,
    const float* __restrict__ pwk, const float* __restrict__ W_out,
    unsigned short* __restrict__ x_bf, unsigned short* __restrict__ Wint,
    unsigned short* __restrict__ pw_t, unsigned short* __restrict__ Woutt)
{
    const int b = blockIdx.x;
    const int t = threadIdx.x;
    if (b < 4096) {                       // cast
        int i = b * 1024 + t * 4;
        float4 v = *(const float4*)&x[i];
        ushort4 o;
        o.x = f2bf(v.x); o.y = f2bf(v.y); o.z = f2bf(v.z); o.w = f2bf(v.w);
        *(ushort4*)&x_bf[i] = o;
        return;
    }
    // transpose-cast: src[R][C] fp32 -> dst[C][R] bf16, 64x64 tile
    const float* src; unsigned short* dst; int R, C, c0, r0;
    if (b < 5120) {
        int bi = b - 4096; src = W_in; dst = Wint; R = 1024; C = 4096;
        c0 = (bi & 63) * 64; r0 = (bi >> 6) * 64;      // 64 x 16 tiles
    } else if (b < 6144) {
        int bi = b - 5120; src = pwk; dst = pw_t; R = 2048; C = 2048;
        c0 = (bi & 31) * 64; r0 = (bi >> 5) * 64;      // 32 x 32 tiles
    } else {
        int bi = b - 6144; src = W_out; dst = Woutt; R = 2048; C = 1024;
        c0 = (bi & 15) * 64; r0 = (bi >> 4) * 64;      // 16 x 32 tiles
    }
    __shared__ float tile[64][65];
    {   // read: 4 passes, float4 per thread (fully vectorized global reads)
        const int rl = t >> 4;            // 0..15 (+16 per pass)
        const int cl = (t & 15) * 4;
#pragma unroll
        for (int p = 0; p < 4; ++p) {
            float4 v = *(const float4*)&src[(size_t)(r0 + p * 16 + rl) * C + c0 + cl];
            tile[p * 16 + rl][cl + 0] = v.x;
            tile[p * 16 + rl][cl + 1] = v.y;
            tile[p * 16 + rl][cl + 2] = v.z;
            tile[p * 16 + rl][cl + 3] = v.w;
        }
    }
    __syncthreads();
    {   // write: 2 passes, ushort8 per thread (16B coalesced global writes)
        const int ccl = t >> 3;           // 0..31 (+32 per pass)
        const int rr  = (t & 7) * 8;
#pragma unroll
        for (int q = 0; q < 2; ++q) {
            int cc = q * 32 + ccl;
            u16x8 o;
#pragma unroll
            for (int j = 0; j < 8; ++j)
                o[j] = (short)f2bf(tile[rr + j][cc]);
            *(u16x8*)&dst[(size_t)(c0 + cc) * R + r0 + rr] = o;
        }
    }
}

// ---------------------------------------------------------------------------
// G4: delta = softplus(xdbl[:, :64] @ W_dt + b_dt)  (fp32; xdbl L2-hot)
// ---------------------------------------------------------------------------
__global__ __launch_bounds__(256) void gemm_tiled_sp(
    const float* __restrict__ A, const float* __restrict__ B,
    float* __restrict__ C, int M, int N, int K,
    int lda, int ldb, int ldc, const float* __restrict__ bias)
{
    __shared__ float As[16][68];
    __shared__ float Bs[16][68];

    const int bm = blockIdx.y * 64;
    const int bn = blockIdx.x * 64;
    const int tid = threadIdx.x;
    const int tx = tid & 15;
    const int ty = tid >> 4;

    float acc[4][4];
#pragma unroll
    for (int i = 0; i < 4; ++i)
#pragma unroll
        for (int j = 0; j < 4; ++j) acc[i][j] = 0.0f;

    const int ar = tid >> 2;
    const int ac = (tid & 3) << 2;
    const int br = tid >> 4;
    const int bc = (tid & 15) << 2;

    for (int k0 = 0; k0 < K; k0 += 16) {
        float4 av = *(const float4*)&A[(size_t)(bm + ar) * lda + k0 + ac];
        float4 bv = *(const float4*)&B[(size_t)(k0 + br) * ldb + bn + bc];
        As[ac + 0][ar] = av.x;
        As[ac + 1][ar] = av.y;
        As[ac + 2][ar] = av.z;
        As[ac + 3][ar] = av.w;
        *(float4*)&Bs[br][bc] = bv;
        __syncthreads();
#pragma unroll
        for (int k = 0; k < 16; ++k) {
            float4 a4 = *(float4*)&As[k][ty * 4];
            float4 b4 = *(float4*)&Bs[k][tx * 4];
            float am[4] = {a4.x, a4.y, a4.z, a4.w};
            float bn4[4] = {b4.x, b4.y, b4.z, b4.w};
#pragma unroll
            for (int i = 0; i < 4; ++i)
#pragma unroll
                for (int j = 0; j < 4; ++j)
                    acc[i][j] = fmaf(am[i], bn4[j], acc[i][j]);
        }
        __syncthreads();
    }

    const int col = bn + tx * 4;
#pragma unroll
    for (int i = 0; i < 4; ++i) {
        int row = bm + ty * 4 + i;
        float4 v = make_float4(acc[i][0], acc[i][1], acc[i][2], acc[i][3]);
        v.x = softplus_f(v.x + bias[col + 0]);
        v.y = softplus_f(v.y + bias[col + 1]);
        v.z = softplus_f(v.z + bias[col + 2]);
        v.w = softplus_f(v.w + bias[col + 3]);
        *(float4*)&C[(size_t)row * ldc + col] = v;
    }
}

// ---------------------------------------------------------------------------
// G3 split-K: part[kc][M][80] = xc_bf[:, kc*256:(kc+1)*256] @ W_x-chunk
// ---------------------------------------------------------------------------
__global__ __launch_bounds__(256) void g3_splitk(
    const unsigned short* __restrict__ xc, const float* __restrict__ Wx,
    float* __restrict__ part)
{
    __shared__ float As[16][68];   // [k][row]
    __shared__ float Bs[16][85];   // [k][col]
    const int m0 = blockIdx.x * 64;
    const int kb = blockIdx.y * G3_KC;
    const int t = threadIdx.x;
    const int tr = t >> 4;
    const int tc = t & 15;

    const int arow = t >> 2;
    const int ak4  = (t & 3) * 4;
    const int bk   = t >> 4;
    const int bc   = (t & 15) * 5;

    float acc[4][5];
#pragma unroll
    for (int r = 0; r < 4; ++r)
#pragma unroll
        for (int c = 0; c < 5; ++c) acc[r][c] = 0.0f;

    for (int k0 = 0; k0 < G3_KC; k0 += 16) {
        ushort4 av = *(const ushort4*)&xc[(size_t)(m0 + arow) * DINNER + kb + k0 + ak4];
        float bv[5];
#pragma unroll
        for (int q = 0; q < 5; ++q)
            bv[q] = Wx[(size_t)(kb + k0 + bk) * 80 + bc + q];
        __syncthreads();
        As[ak4 + 0][arow] = bf2f(av.x);
        As[ak4 + 1][arow] = bf2f(av.y);
        As[ak4 + 2][arow] = bf2f(av.z);
        As[ak4 + 3][arow] = bf2f(av.w);
#pragma unroll
        for (int q = 0; q < 5; ++q) Bs[bk][bc + q] = bv[q];
        __syncthreads();
#pragma unroll
        for (int k = 0; k < 16; ++k) {
            float a[4], b[5];
#pragma unroll
            for (int r = 0; r < 4; ++r) a[r] = As[k][tr * 4 + r];
#pragma unroll
            for (int c = 0; c < 5; ++c) b[c] = Bs[k][tc * 5 + c];
#pragma unroll
            for (int r = 0; r < 4; ++r)
#pragma unroll
                for (int c = 0; c < 5; ++c)
                    acc[r][c] = fmaf(a[r], b[c], acc[r][c]);
        }
    }
#pragma unroll
    for (int r = 0; r < 4; ++r)
#pragma unroll
        for (int c = 0; c < 5; ++c)
            part[((size_t)blockIdx.y * MM + m0 + tr * 4 + r) * 80 + tc * 5 + c] = acc[r][c];
}

// reduce 8 partials -> xdbl (1.25 MB; keeps g4/p1/p3 off the 8x L3 re-read)
__global__ __launch_bounds__(256) void g3_reduce(
    const float* __restrict__ part, float* __restrict__ xdbl)
{
    int i = (blockIdx.x * 256 + threadIdx.x) * 4;
    if (i >= MM * 80) return;
    float4 s = *(const float4*)&part[i];
#pragma unroll
    for (int c = 1; c < G3_KCH; ++c) {
        float4 p = *(const float4*)&part[(size_t)c * MM * 80 + i];
        s.x += p.x; s.y += p.y; s.z += p.z; s.w += p.w;
    }
    *(float4*)&xdbl[i] = s;
}

// ---------------------------------------------------------------------------
// Depthwise causal conv on dense bf16 x_in [M][DINNER]; bf16 out; x4 vector.
// ---------------------------------------------------------------------------
__global__ __launch_bounds__(256) void dwconv_kernel(
    const unsigned short* __restrict__ x_in, const float* __restrict__ dwk,
    unsigned short* __restrict__ out)
{
    int i4 = blockIdx.x * 256 + threadIdx.x;
    if (i4 >= MM * DINNER / 4) return;
    int d = (i4 * 4) & (DINNER - 1);
    int bl = (i4 * 4) >> 11;
    int l = bl & (Ll - 1);
    int b = bl >> 11;
    float a0 = 0.f, a1 = 0.f, a2 = 0.f, a3 = 0.f;
#pragma unroll
    for (int k = 0; k < DCONV; ++k) {
        int t = l + k - (DCONV - 1);
        if (t >= 0) {
            ushort4 xv = *(const ushort4*)&x_in[(size_t)(b * Ll + t) * DINNER + d];
            float4 wv = *(const float4*)&dwk[k * DINNER + d];
            a0 = fmaf(bf2f(xv.x), wv.x, a0);
            a1 = fmaf(bf2f(xv.y), wv.y, a1);
            a2 = fmaf(bf2f(xv.z), wv.z, a2);
            a3 = fmaf(bf2f(xv.w), wv.w, a3);
        }
    }
    ushort4 o;
    o.x = f2bf(a0); o.y = f2bf(a1); o.z = f2bf(a2); o.w = f2bf(a3);
    *(ushort4*)&out[i4 * 4] = o;
}

// ---------------------------------------------------------------------------
// Selective scan pass 1: per-chunk local scan from h=0. CL=64.
// ---------------------------------------------------------------------------
__global__ __launch_bounds__(256) void scan_pass1(
    const float* __restrict__ delta, const unsigned short* __restrict__ xc,
    const float* __restrict__ xdbl, const float* __restrict__ A_log,
    float* __restrict__ cs_a, float* __restrict__ cs_h)
{
    const int d = blockIdx.x * 256 + threadIdx.x;
    const int c = blockIdx.y;
    const int b = blockIdx.z;
    const int t0 = c * CL;

    __shared__ float sB[CL][8];
    {   // CL*8 = 512 elems, 2 per thread
        int i = threadIdx.x;
#pragma unroll
        for (int half = 0; half < 2; ++half) {
            int ii = i + half * 256;
            int t = ii >> 3, j = ii & 7;
            sB[t][j] = xdbl[((size_t)(b * Ll + t0 + t)) * 80 + DTRANK + j];
        }
    }
    __syncthreads();

    float An[8];
#pragma unroll
    for (int n = 0; n < 8; ++n) An[n] = -__expf(A_log[d * 8 + n]);

    float h[8], ap[8];
#pragma unroll
    for (int n = 0; n < 8; ++n) { h[n] = 0.0f; ap[n] = 1.0f; }

    const float* dptr = delta + ((size_t)(b * Ll + t0)) * DINNER + d;
    const unsigned short* xptr = xc + ((size_t)(b * Ll + t0)) * DINNER + d;

#pragma unroll 4
    for (int t = 0; t < CL; ++t) {
        float dl = dptr[(size_t)t * DINNER];
        float xv = bf2f(xptr[(size_t)t * DINNER]);
        float du = dl * xv;
#pragma unroll
        for (int n = 0; n < 8; ++n) {
            float dA = __expf(dl * An[n]);
            h[n] = fmaf(dA, h[n], du * sB[t][n]);
            ap[n] *= dA;
        }
    }

    size_t base = (((size_t)(b * NCH + c)) * 8) * DINNER + d;
#pragma unroll
    for (int n = 0; n < 8; ++n) {
        cs_a[base + (size_t)n * DINNER] = ap[n];
        cs_h[base + (size_t)n * DINNER] = h[n];
    }
}

// Pass 2: sequential combine (NCH=32 iters); hin ALIASES cs_h (in-place).
__global__ __launch_bounds__(256) void scan_pass2(
    const float* __restrict__ cs_a, const float* cs_h, float* hin)
{
    int idx = blockIdx.x * 256 + threadIdx.x;
    if (idx >= Bb * 8 * DINNER) return;
    int d = idx & (DINNER - 1);
    int n = (idx >> 11) & 7;
    int b = idx >> 14;
    float H = 0.0f;
#pragma unroll 4
    for (int c = 0; c < NCH; ++c) {
        size_t o = (((size_t)(b * NCH + c)) * 8 + n) * DINNER + d;
        float a = cs_a[o];
        float hh = cs_h[o];
        hin[o] = H;
        H = fmaf(a, H, hh);
    }
}

// Pass 3: replay with correct h_in; fused epilogue -> bf16 y. CL=64.
__global__ __launch_bounds__(256) void scan_pass3(
    const float* __restrict__ delta, const unsigned short* __restrict__ xc,
    const float* __restrict__ xdbl, const float* __restrict__ A_log,
    const float* __restrict__ hin, const unsigned short* __restrict__ z,
    const float* __restrict__ Dvec, unsigned short* __restrict__ y_bf)
{
    const int d = blockIdx.x * 256 + threadIdx.x;
    const int c = blockIdx.y;
    const int b = blockIdx.z;
    const int t0 = c * CL;

    __shared__ float sB[CL][8];
    __shared__ float sC[CL][8];
    {   // CL*16 = 1024 elems, 4 per thread
        int i = threadIdx.x;
#pragma unroll
        for (int q = 0; q < 4; ++q) {
            int ii = i + q * 256;
            int t = ii >> 4, j = ii & 15;
            float v = xdbl[((size_t)(b * Ll + t0 + t)) * 80 + DTRANK + j];
            if (j < 8) sB[t][j] = v; else sC[t][j - 8] = v;
        }
    }
    __syncthreads();

    float An[8];
#pragma unroll
    for (int n = 0; n < 8; ++n) An[n] = -__expf(A_log[d * 8 + n]);

    float h[8];
    size_t hbase = (((size_t)(b * NCH + c)) * 8) * DINNER + d;
#pragma unroll
    for (int n = 0; n < 8; ++n) h[n] = hin[hbase + (size_t)n * DINNER];

    const float Dd = Dvec[d];
    const float* dptr = delta + ((size_t)(b * Ll + t0)) * DINNER + d;
    const unsigned short* xptr = xc + ((size_t)(b * Ll + t0)) * DINNER + d;
    const unsigned short* zptr = z + ((size_t)(b * Ll + t0)) * DINNER + d;
    unsigned short* yptr = y_bf + ((size_t)(b * Ll + t0)) * DINNER + d;

    for (int t = 0; t < CL; ++t) {
        float dl = dptr[(size_t)t * DINNER];
        float xv = bf2f(xptr[(size_t)t * DINNER]);
        float du = dl * xv;
        float yt = 0.0f;
#pragma unroll
        for (int n = 0; n < 8; ++n) {
            float dA = __expf(dl * An[n]);
            h[n] = fmaf(dA, h[n], du * sB[t][n]);
            yt = fmaf(sC[t][n], h[n], yt);
        }
        float zv = bf2f(zptr[(size_t)t * DINNER]);
        yptr[(size_t)t * DINNER] = f2bf((yt + xv * Dd) * silu_f(zv));
    }
}

// ---------------------------------------------------------------------------
extern "C" void kernel_launch(void* const* d_in, const int* in_sizes, int n_in,
                              void* d_out, int out_size, void* d_ws, size_t ws_size,
                              hipStream_t stream)
{
    const float* x         = (const float*)d_in[0];
    const float* W_in      = (const float*)d_in[1];
    const float* dwk       = (const float*)d_in[2];
    const float* pwk       = (const float*)d_in[3];
    const float* conv_bias = (const float*)d_in[4];
    const float* W_x       = (const float*)d_in[5];
    const float* W_dt      = (const float*)d_in[6];
    const float* b_dt      = (const float*)d_in[7];
    const float* A_log     = (const float*)d_in[8];
    const float* Dv        = (const float*)d_in[9];
    const float* W_out     = (const float*)d_in[10];
    float* out = (float*)d_out;

    // workspace map (MiB offsets; peak 152 MiB <= proven 154)
    char* ws = (char*)d_ws;
    unsigned short* x_in_bf = (unsigned short*)(ws);                  // [0,16)   G1..conv
    unsigned short* z_bf    = (unsigned short*)(ws + (16ull << 20));  // [16,32)  G1..p3
    float*          delta   = (float*)(ws + (32ull << 20));           // [32,64)  G4..p3
    unsigned short* x_bf    = (unsigned short*)(ws + (64ull << 20));  // [64,72)  prep..G1
    unsigned short* y_bf    = (unsigned short*)(ws + (64ull << 20));  // [64,80)  p3..G5
    unsigned short* Wint    = (unsigned short*)(ws + (72ull << 20));  // [72,80)  prep..G1
    unsigned short* pw_t    = (unsigned short*)(ws + (80ull << 20));  // [80,88)  prep..G2
    unsigned short* xcp_bf  = (unsigned short*)(ws + (88ull << 20));  // [88,104) conv..G2
    unsigned short* xc_bf   = (unsigned short*)(ws + (104ull << 20)); // [104,120) G2..p3
    unsigned short* Woutt   = (unsigned short*)(ws + (120ull << 20)); // [120,124) prep..G5
    float*          xdbl    = (float*)(ws + (124ull << 20));          // [124,125.4) g3red..p3
    float*          g3part  = (float*)(ws + (126ull << 20));          // [126,136) g3..g3red
    float*          cs_a    = (float*)(ws + (136ull << 20));          // [136,140) p1..p2 (4 MB)
    float*          cs_h    = (float*)(ws + (144ull << 20));          // [144,148) p1..p3 (4 MB)
    float*          hin     = cs_h;   // in-place
    dim3 blk(256);

    // prep: cast + 3 transposes fused into one dispatch (64x64 vectorized)
    prep_all<<<6656, blk, 0, stream>>>(x, W_in, pwk, W_out,
                                       x_bf, Wint, pw_t, Woutt);

    // G1: xz = x @ W_in, deinterleaved bf16 (x_in | z). NW=4, TN=128.
    mfma_gemm<0, 4, 128, unsigned short>
        <<<dim3((2 * DINNER) / 128, MM / 128), blk, 0, stream>>>(
        x_bf, Wint, x_in_bf, z_bf, DINNER,
        MM, 2 * DINNER, DMODEL, DMODEL, DMODEL, DINNER, nullptr);

    // depthwise causal conv (bf16 in, bf16 out)
    dwconv_kernel<<<MM * DINNER / 4 / 256, blk, 0, stream>>>(x_in_bf, dwk, xcp_bf);

    // G2: xc = silu(conv @ pw + conv_bias) -> bf16. NW=8, TN=128 (winner).
    mfma_gemm<1, 8, 128, unsigned short>
        <<<dim3(DINNER / 128, MM / 128), dim3(512), 0, stream>>>(
        xcp_bf, pw_t, xc_bf, xc_bf, DINNER + 1,
        MM, DINNER, DINNER, DINNER, DINNER, DINNER, conv_bias);

    // G3: x_dbl partials = xc @ W_x (split-K fp32) + materialized reduce
    g3_splitk<<<dim3(MM / 64, G3_KCH), blk, 0, stream>>>(xc_bf, W_x, g3part);
    g3_reduce<<<(MM * 80 / 4 + 255) / 256, blk, 0, stream>>>(g3part, xdbl);

    // G4: delta = softplus(xdbl[:, :64] @ W_dt + b_dt)  (fp32, xdbl L2-hot)
    gemm_tiled_sp<<<dim3(DINNER / 64, MM / 64), blk, 0, stream>>>(
        xdbl, W_dt, delta, MM, DINNER, DTRANK, 80, DINNER, DINNER, b_dt);

    // selective scan, 3-pass chunked (CL=64, NCH=32)
    scan_pass1<<<dim3(DINNER / 256, NCH, Bb), blk, 0, stream>>>(
        delta, xc_bf, xdbl, A_log, cs_a, cs_h);
    scan_pass2<<<(Bb * 8 * DINNER + 255) / 256, blk, 0, stream>>>(cs_a, cs_h, hin);
    scan_pass3<<<dim3(DINNER / 256, NCH, Bb), blk, 0, stream>>>(
        delta, xc_bf, xdbl, A_log, hin, z_bf, Dv, y_bf);

    // G5: out = y @ W_out. NW=4, TN=64 -> 512 blocks, direct write.
    mfma_gemm<0, 4, 64, float>
        <<<dim3(DMODEL / 64, MM / 128), blk, 0, stream>>>(
        y_bf, Woutt, out, out, DMODEL + 1,
        MM, DMODEL, DINNER, DINNER, DINNER, DMODEL, nullptr);
}

// Round 13
// 381.408 us; speedup vs baseline: 1.0523x; 1.0523x over previous
//
#include <hip/hip_runtime.h>
#include <math.h>

// Problem constants
#define Bb 2
#define Ll 2048
#define DMODEL 1024
#define DINNER 2048
#define DSTATE 8
#define DTRANK 64
#define DCONV 4
#define MM (Bb*Ll)          // 4096 rows
// scan chunking (CL=32 proven best: r12's CL=64 halved p1/p3 occupancy, +24us)
#define NCH 64
#define CL 32               // NCH*CL == Ll
// G3 split-K
#define G3_KCH 8
#define G3_KC (DINNER / G3_KCH)   // 256

typedef __attribute__((ext_vector_type(8))) short    bf16x8;
typedef __attribute__((ext_vector_type(4))) float    f32x4;

__device__ __forceinline__ float silu_f(float x) {
    return x / (1.0f + __expf(-x));
}
__device__ __forceinline__ float softplus_f(float x) {
    return fmaxf(x, 0.0f) + log1pf(__expf(-fabsf(x)));
}
__device__ __forceinline__ unsigned short f2bf(float f) {
    unsigned int u = __float_as_uint(f);
    u += 0x7fffu + ((u >> 16) & 1u);      // RNE
    return (unsigned short)(u >> 16);
}
__device__ __forceinline__ float bf2f(unsigned short u) {
    return __uint_as_float(((unsigned int)u) << 16);
}
// async 16B global->LDS (wave-uniform LDS base + lane*16 dest)
__device__ __forceinline__ void async_cp16(const unsigned short* g, unsigned short* l) {
    __builtin_amdgcn_global_load_lds(
        (const __attribute__((address_space(1))) void*)g,
        (__attribute__((address_space(3))) void*)l, 16, 0, 0);
}

// ---------------------------------------------------------------------------
// bf16 MFMA GEMM (r11-proven): NW waves, tile 128 x TN, BK=32, double-
// buffered async staging, flat LDS + 16B-slot XOR swizzle -> 0 bank
// conflicts. ~650-670 TF structural plateau (1-barrier K-loop, m97-class);
// measured invariant across NW/TN/split-K (r5-r11).
// ---------------------------------------------------------------------------
template <int EPI, int NW, int TN, typename OT>
__global__ __launch_bounds__(NW * 64, 4) void mfma_gemm(
    const unsigned short* __restrict__ A, const unsigned short* __restrict__ Bt,
    OT* __restrict__ C, OT* __restrict__ C2, int nsplit,
    int M, int N, int K, int lda, int ldb, int ldc,
    const float* __restrict__ bias)
{
    constexpr int NT   = NW * 64;     // threads
    constexpr int WNC  = NW / 2;      // waves along n
    constexpr int WNE  = TN / WNC;    // wave n-extent
    constexpr int NJ   = WNE / 16;    // b-frags per wave
    constexpr int RPP  = NT / 4;      // tile rows staged per pass
    constexpr int APASS = 128 / RPP;
    constexpr int BPASS = TN / RPP;

    __shared__ unsigned short As[2][128 * 32];   // 2 x 8 KB
    __shared__ unsigned short Bs[2][TN * 32];

    const int bm = blockIdx.y * 128;
    const int bn = blockIdx.x * TN;
    const int tid  = threadIdx.x;
    const int w    = tid >> 6;
    const int lane = tid & 63;
    const int wm = (w / WNC) * 64;
    const int wn = (w % WNC) * WNE;
    const int lr = lane & 15;
    const int lq = lane >> 4;

    // staging: thread t covers row t>>2 (+p*RPP per pass), 16B slot t&3.
    // Swizzle applied on the GLOBAL column; (row + p*RPP)>>1 mod 4 invariant.
    const int row  = tid >> 2;
    const int sp   = tid & 3;
    const int slog = sp ^ ((row >> 1) & 3);
    const unsigned short* gA = A  + (size_t)(bm + row) * lda + slog * 8;
    const unsigned short* gB = Bt + (size_t)(bn + row) * ldb + slog * 8;
    const int st = tid * 8;

    // fragment read offset (logical slot lq at phys slot lq^((lr>>1)&3))
    const int fsw = (lq ^ ((lr >> 1) & 3)) * 8;

    f32x4 acc[4][NJ];
#pragma unroll
    for (int i = 0; i < 4; ++i)
#pragma unroll
        for (int j = 0; j < NJ; ++j) acc[i][j] = (f32x4){0.f, 0.f, 0.f, 0.f};

    // prologue: tile 0 -> buffer 0
#pragma unroll
    for (int p = 0; p < APASS; ++p)
        async_cp16(gA + (size_t)p * RPP * lda, &As[0][p * RPP * 32 + st]);
#pragma unroll
    for (int p = 0; p < BPASS; ++p)
        async_cp16(gB + (size_t)p * RPP * ldb, &Bs[0][p * RPP * 32 + st]);

    int cur = 0;
    for (int k0 = 0; k0 < K; k0 += 32, cur ^= 1) {
        __syncthreads();   // drains tile-k loads (vmcnt) + prev ds_reads (lgkm)
        const int nk = k0 + 32;
        if (nk < K) {
            const int nb = cur ^ 1;
#pragma unroll
            for (int p = 0; p < APASS; ++p)
                async_cp16(gA + (size_t)p * RPP * lda + nk, &As[nb][p * RPP * 32 + st]);
#pragma unroll
            for (int p = 0; p < BPASS; ++p)
                async_cp16(gB + (size_t)p * RPP * ldb + nk, &Bs[nb][p * RPP * 32 + st]);
        }

        bf16x8 a[4], b[NJ];
#pragma unroll
        for (int i = 0; i < 4; ++i)
            a[i] = *(const bf16x8*)&As[cur][(wm + i * 16 + lr) * 32 + fsw];
#pragma unroll
        for (int j = 0; j < NJ; ++j)
            b[j] = *(const bf16x8*)&Bs[cur][(wn + j * 16 + lr) * 32 + fsw];
#pragma unroll
        for (int i = 0; i < 4; ++i)
#pragma unroll
            for (int j = 0; j < NJ; ++j)
                acc[i][j] = __builtin_amdgcn_mfma_f32_16x16x32_bf16(
                    a[i], b[j], acc[i][j], 0, 0, 0);
    }

    // epilogue: C/D layout col = lane&15, row = (lane>>4)*4 + reg
#pragma unroll
    for (int i = 0; i < 4; ++i) {
        const int row0 = bm + wm + i * 16 + lq * 4;
#pragma unroll
        for (int j = 0; j < NJ; ++j) {
            const int col = bn + wn + j * 16 + lr;
            OT* Cb; int colb;
            if (col < nsplit) { Cb = C; colb = col; }
            else              { Cb = C2; colb = col - nsplit; }
            float bv = (EPI == 1) ? bias[col] : 0.0f;
#pragma unroll
            for (int r = 0; r < 4; ++r) {
                float v = acc[i][j][r];
                if (EPI == 1) v = silu_f(v + bv);
                if (sizeof(OT) == 2)
                    Cb[(size_t)(row0 + r) * ldc + colb] = (OT)f2bf(v);
                else
                    Cb[(size_t)(row0 + r) * ldc + colb] = (OT)v;
            }
        }
    }
}

// ---------------------------------------------------------------------------
// prep_all: ONE kernel for input cast + 3 weight transpose-casts. Ranges:
//   [0,4096)      cast x -> bf16 (1024 elems/block)
//   [4096,8192)   W_in  [1024][4096] -> Wint  [4096][1024]
//   [8192,12288)  pwk   [2048][2048] -> pw_t  [2048][2048]
//   [12288,14336) W_out [2048][1024] -> Woutt [1024][2048]
// ---------------------------------------------------------------------------
__global__ __launch_bounds__(256) void prep_all(
    const float* __restrict__ x, const float* __restrict__ W_in,
    const float* __restrict__ pwk, const float* __restrict__ W_out,
    unsigned short* __restrict__ x_bf, unsigned short* __restrict__ Wint,
    unsigned short* __restrict__ pw_t, unsigned short* __restrict__ Woutt)
{
    const int b = blockIdx.x;
    const int t = threadIdx.x;
    if (b < 4096) {                       // cast
        int i = b * 1024 + t * 4;
        float4 v = *(const float4*)&x[i];
        ushort4 o;
        o.x = f2bf(v.x); o.y = f2bf(v.y); o.z = f2bf(v.z); o.w = f2bf(v.w);
        *(ushort4*)&x_bf[i] = o;
        return;
    }
    // transpose-cast: src[R][C] -> dst[C][R], 32x32 tile
    const float* src; unsigned short* dst; int R, C, c0, r0;
    if (b < 8192) {
        int bi = b - 4096; src = W_in; dst = Wint; R = 1024; C = 4096;
        c0 = (bi & 127) * 32; r0 = (bi >> 7) * 32;
    } else if (b < 12288) {
        int bi = b - 8192; src = pwk; dst = pw_t; R = 2048; C = 2048;
        c0 = (bi & 63) * 32; r0 = (bi >> 6) * 32;
    } else {
        int bi = b - 12288; src = W_out; dst = Woutt; R = 2048; C = 1024;
        c0 = (bi & 31) * 32; r0 = (bi >> 5) * 32;
    }
    __shared__ float tile[32][33];
    const int tx = t & 31;
    const int ty = t >> 5;                // 0..7
#pragma unroll
    for (int i = 0; i < 32; i += 8)
        tile[ty + i][tx] = src[(size_t)(r0 + ty + i) * C + c0 + tx];
    __syncthreads();
#pragma unroll
    for (int i = 0; i < 32; i += 8)
        dst[(size_t)(c0 + ty + i) * R + r0 + tx] = f2bf(tile[tx][ty + i]);
}

// ---------------------------------------------------------------------------
// G4: delta = softplus(xdbl[:, :64] @ W_dt + b_dt)  (fp32; xdbl is the
// materialized 1.25 MB reduce of g3 partials -> L2/L3-resident, no 8x re-read)
// ---------------------------------------------------------------------------
__global__ __launch_bounds__(256) void gemm_tiled_sp(
    const float* __restrict__ A, const float* __restrict__ B,
    float* __restrict__ C, int M, int N, int K,
    int lda, int ldb, int ldc, const float* __restrict__ bias)
{
    __shared__ float As[16][68];
    __shared__ float Bs[16][68];

    const int bm = blockIdx.y * 64;
    const int bn = blockIdx.x * 64;
    const int tid = threadIdx.x;
    const int tx = tid & 15;
    const int ty = tid >> 4;

    float acc[4][4];
#pragma unroll
    for (int i = 0; i < 4; ++i)
#pragma unroll
        for (int j = 0; j < 4; ++j) acc[i][j] = 0.0f;

    const int ar = tid >> 2;
    const int ac = (tid & 3) << 2;
    const int br = tid >> 4;
    const int bc = (tid & 15) << 2;

    for (int k0 = 0; k0 < K; k0 += 16) {
        float4 av = *(const float4*)&A[(size_t)(bm + ar) * lda + k0 + ac];
        float4 bv = *(const float4*)&B[(size_t)(k0 + br) * ldb + bn + bc];
        As[ac + 0][ar] = av.x;
        As[ac + 1][ar] = av.y;
        As[ac + 2][ar] = av.z;
        As[ac + 3][ar] = av.w;
        *(float4*)&Bs[br][bc] = bv;
        __syncthreads();
#pragma unroll
        for (int k = 0; k < 16; ++k) {
            float4 a4 = *(float4*)&As[k][ty * 4];
            float4 b4 = *(float4*)&Bs[k][tx * 4];
            float am[4] = {a4.x, a4.y, a4.z, a4.w};
            float bn4[4] = {b4.x, b4.y, b4.z, b4.w};
#pragma unroll
            for (int i = 0; i < 4; ++i)
#pragma unroll
                for (int j = 0; j < 4; ++j)
                    acc[i][j] = fmaf(am[i], bn4[j], acc[i][j]);
        }
        __syncthreads();
    }

    const int col = bn + tx * 4;
#pragma unroll
    for (int i = 0; i < 4; ++i) {
        int row = bm + ty * 4 + i;
        float4 v = make_float4(acc[i][0], acc[i][1], acc[i][2], acc[i][3]);
        v.x = softplus_f(v.x + bias[col + 0]);
        v.y = softplus_f(v.y + bias[col + 1]);
        v.z = softplus_f(v.z + bias[col + 2]);
        v.w = softplus_f(v.w + bias[col + 3]);
        *(float4*)&C[(size_t)row * ldc + col] = v;
    }
}

// ---------------------------------------------------------------------------
// G3 split-K: part[kc][M][80] = xc_bf[:, kc*256:(kc+1)*256] @ W_x-chunk
// ---------------------------------------------------------------------------
__global__ __launch_bounds__(256) void g3_splitk(
    const unsigned short* __restrict__ xc, const float* __restrict__ Wx,
    float* __restrict__ part)
{
    __shared__ float As[16][68];   // [k][row]
    __shared__ float Bs[16][85];   // [k][col]
    const int m0 = blockIdx.x * 64;
    const int kb = blockIdx.y * G3_KC;
    const int t = threadIdx.x;
    const int tr = t >> 4;
    const int tc = t & 15;

    const int arow = t >> 2;
    const int ak4  = (t & 3) * 4;
    const int bk   = t >> 4;
    const int bc   = (t & 15) * 5;

    float acc[4][5];
#pragma unroll
    for (int r = 0; r < 4; ++r)
#pragma unroll
        for (int c = 0; c < 5; ++c) acc[r][c] = 0.0f;

    for (int k0 = 0; k0 < G3_KC; k0 += 16) {
        ushort4 av = *(const ushort4*)&xc[(size_t)(m0 + arow) * DINNER + kb + k0 + ak4];
        float bv[5];
#pragma unroll
        for (int q = 0; q < 5; ++q)
            bv[q] = Wx[(size_t)(kb + k0 + bk) * 80 + bc + q];
        __syncthreads();
        As[ak4 + 0][arow] = bf2f(av.x);
        As[ak4 + 1][arow] = bf2f(av.y);
        As[ak4 + 2][arow] = bf2f(av.z);
        As[ak4 + 3][arow] = bf2f(av.w);
#pragma unroll
        for (int q = 0; q < 5; ++q) Bs[bk][bc + q] = bv[q];
        __syncthreads();
#pragma unroll
        for (int k = 0; k < 16; ++k) {
            float a[4], b[5];
#pragma unroll
            for (int r = 0; r < 4; ++r) a[r] = As[k][tr * 4 + r];
#pragma unroll
            for (int c = 0; c < 5; ++c) b[c] = Bs[k][tc * 5 + c];
#pragma unroll
            for (int r = 0; r < 4; ++r)
#pragma unroll
                for (int c = 0; c < 5; ++c)
                    acc[r][c] = fmaf(a[r], b[c], acc[r][c]);
        }
    }
#pragma unroll
    for (int r = 0; r < 4; ++r)
#pragma unroll
        for (int c = 0; c < 5; ++c)
            part[((size_t)blockIdx.y * MM + m0 + tr * 4 + r) * 80 + tc * 5 + c] = acc[r][c];
}

// reduce 8 partials -> xdbl (1.25 MB; keeps g4/p1/p3 off the 8x L3 re-read)
__global__ __launch_bounds__(256) void g3_reduce(
    const float* __restrict__ part, float* __restrict__ xdbl)
{
    int i = (blockIdx.x * 256 + threadIdx.x) * 4;
    if (i >= MM * 80) return;
    float4 s = *(const float4*)&part[i];
#pragma unroll
    for (int c = 1; c < G3_KCH; ++c) {
        float4 p = *(const float4*)&part[(size_t)c * MM * 80 + i];
        s.x += p.x; s.y += p.y; s.z += p.z; s.w += p.w;
    }
    *(float4*)&xdbl[i] = s;
}

// ---------------------------------------------------------------------------
// Depthwise causal conv on dense bf16 x_in [M][DINNER]; bf16 out; x4 vector.
// ---------------------------------------------------------------------------
__global__ __launch_bounds__(256) void dwconv_kernel(
    const unsigned short* __restrict__ x_in, const float* __restrict__ dwk,
    unsigned short* __restrict__ out)
{
    int i4 = blockIdx.x * 256 + threadIdx.x;
    if (i4 >= MM * DINNER / 4) return;
    int d = (i4 * 4) & (DINNER - 1);
    int bl = (i4 * 4) >> 11;
    int l = bl & (Ll - 1);
    int b = bl >> 11;
    float a0 = 0.f, a1 = 0.f, a2 = 0.f, a3 = 0.f;
#pragma unroll
    for (int k = 0; k < DCONV; ++k) {
        int t = l + k - (DCONV - 1);
        if (t >= 0) {
            ushort4 xv = *(const ushort4*)&x_in[(size_t)(b * Ll + t) * DINNER + d];
            float4 wv = *(const float4*)&dwk[k * DINNER + d];
            a0 = fmaf(bf2f(xv.x), wv.x, a0);
            a1 = fmaf(bf2f(xv.y), wv.y, a1);
            a2 = fmaf(bf2f(xv.z), wv.z, a2);
            a3 = fmaf(bf2f(xv.w), wv.w, a3);
        }
    }
    ushort4 o;
    o.x = f2bf(a0); o.y = f2bf(a1); o.z = f2bf(a2); o.w = f2bf(a3);
    *(ushort4*)&out[i4 * 4] = o;
}

// ---------------------------------------------------------------------------
// Selective scan pass 1: per-chunk local scan from h=0. xc is bf16.
// sB from xdbl (materialized reduce).
// ---------------------------------------------------------------------------
__global__ __launch_bounds__(256) void scan_pass1(
    const float* __restrict__ delta, const unsigned short* __restrict__ xc,
    const float* __restrict__ xdbl, const float* __restrict__ A_log,
    float* __restrict__ cs_a, float* __restrict__ cs_h)
{
    const int d = blockIdx.x * 256 + threadIdx.x;
    const int c = blockIdx.y;
    const int b = blockIdx.z;
    const int t0 = c * CL;

    __shared__ float sB[CL][8];
    {
        int i = threadIdx.x;
        int t = i >> 3, j = i & 7;
        sB[t][j] = xdbl[((size_t)(b * Ll + t0 + t)) * 80 + DTRANK + j];
    }
    __syncthreads();

    float An[8];
#pragma unroll
    for (int n = 0; n < 8; ++n) An[n] = -__expf(A_log[d * 8 + n]);

    float h[8], ap[8];
#pragma unroll
    for (int n = 0; n < 8; ++n) { h[n] = 0.0f; ap[n] = 1.0f; }

    const float* dptr = delta + ((size_t)(b * Ll + t0)) * DINNER + d;
    const unsigned short* xptr = xc + ((size_t)(b * Ll + t0)) * DINNER + d;

#pragma unroll 4
    for (int t = 0; t < CL; ++t) {
        float dl = dptr[(size_t)t * DINNER];
        float xv = bf2f(xptr[(size_t)t * DINNER]);
        float du = dl * xv;
#pragma unroll
        for (int n = 0; n < 8; ++n) {
            float dA = __expf(dl * An[n]);
            h[n] = fmaf(dA, h[n], du * sB[t][n]);
            ap[n] *= dA;
        }
    }

    size_t base = (((size_t)(b * NCH + c)) * 8) * DINNER + d;
#pragma unroll
    for (int n = 0; n < 8; ++n) {
        cs_a[base + (size_t)n * DINNER] = ap[n];
        cs_h[base + (size_t)n * DINNER] = h[n];
    }
}

// Pass 2: sequential combine; hin ALIASES cs_h (in-place) — read-before-write.
__global__ __launch_bounds__(256) void scan_pass2(
    const float* __restrict__ cs_a, const float* cs_h, float* hin)
{
    int idx = blockIdx.x * 256 + threadIdx.x;
    if (idx >= Bb * 8 * DINNER) return;
    int d = idx & (DINNER - 1);
    int n = (idx >> 11) & 7;
    int b = idx >> 14;
    float H = 0.0f;
#pragma unroll 4
    for (int c = 0; c < NCH; ++c) {
        size_t o = (((size_t)(b * NCH + c)) * 8 + n) * DINNER + d;
        float a = cs_a[o];
        float hh = cs_h[o];
        hin[o] = H;
        H = fmaf(a, H, hh);
    }
}

// Pass 3: replay with correct h_in; fused epilogue -> bf16 y. z dense bf16.
// sB/sC from xdbl.
__global__ __launch_bounds__(256) void scan_pass3(
    const float* __restrict__ delta, const unsigned short* __restrict__ xc,
    const float* __restrict__ xdbl, const float* __restrict__ A_log,
    const float* __restrict__ hin, const unsigned short* __restrict__ z,
    const float* __restrict__ Dvec, unsigned short* __restrict__ y_bf)
{
    const int d = blockIdx.x * 256 + threadIdx.x;
    const int c = blockIdx.y;
    const int b = blockIdx.z;
    const int t0 = c * CL;

    __shared__ float sB[CL][8];
    __shared__ float sC[CL][8];
    {
        int i = threadIdx.x;
        int t = i >> 4, j = i & 15;
        float v = xdbl[((size_t)(b * Ll + t0 + t)) * 80 + DTRANK + j];
        if (j < 8) sB[t][j] = v; else sC[t][j - 8] = v;
        t = (i + 256) >> 4; j = (i + 256) & 15;
        v = xdbl[((size_t)(b * Ll + t0 + t)) * 80 + DTRANK + j];
        if (j < 8) sB[t][j] = v; else sC[t][j - 8] = v;
    }
    __syncthreads();

    float An[8];
#pragma unroll
    for (int n = 0; n < 8; ++n) An[n] = -__expf(A_log[d * 8 + n]);

    float h[8];
    size_t hbase = (((size_t)(b * NCH + c)) * 8) * DINNER + d;
#pragma unroll
    for (int n = 0; n < 8; ++n) h[n] = hin[hbase + (size_t)n * DINNER];

    const float Dd = Dvec[d];
    const float* dptr = delta + ((size_t)(b * Ll + t0)) * DINNER + d;
    const unsigned short* xptr = xc + ((size_t)(b * Ll + t0)) * DINNER + d;
    const unsigned short* zptr = z + ((size_t)(b * Ll + t0)) * DINNER + d;
    unsigned short* yptr = y_bf + ((size_t)(b * Ll + t0)) * DINNER + d;

    for (int t = 0; t < CL; ++t) {
        float dl = dptr[(size_t)t * DINNER];
        float xv = bf2f(xptr[(size_t)t * DINNER]);
        float du = dl * xv;
        float yt = 0.0f;
#pragma unroll
        for (int n = 0; n < 8; ++n) {
            float dA = __expf(dl * An[n]);
            h[n] = fmaf(dA, h[n], du * sB[t][n]);
            yt = fmaf(sC[t][n], h[n], yt);
        }
        float zv = bf2f(zptr[(size_t)t * DINNER]);
        yptr[(size_t)t * DINNER] = f2bf((yt + xv * Dd) * silu_f(zv));
    }
}

// ---------------------------------------------------------------------------
extern "C" void kernel_launch(void* const* d_in, const int* in_sizes, int n_in,
                              void* d_out, int out_size, void* d_ws, size_t ws_size,
                              hipStream_t stream)
{
    const float* x         = (const float*)d_in[0];
    const float* W_in      = (const float*)d_in[1];
    const float* dwk       = (const float*)d_in[2];
    const float* pwk       = (const float*)d_in[3];
    const float* conv_bias = (const float*)d_in[4];
    const float* W_x       = (const float*)d_in[5];
    const float* W_dt      = (const float*)d_in[6];
    const float* b_dt      = (const float*)d_in[7];
    const float* A_log     = (const float*)d_in[8];
    const float* Dv        = (const float*)d_in[9];
    const float* W_out     = (const float*)d_in[10];
    float* out = (float*)d_out;

    // workspace map (MiB offsets; peak 152 MiB <= proven 154)
    char* ws = (char*)d_ws;
    unsigned short* x_in_bf = (unsigned short*)(ws);                  // [0,16)   G1..conv
    unsigned short* z_bf    = (unsigned short*)(ws + (16ull << 20));  // [16,32)  G1..p3
    float*          delta   = (float*)(ws + (32ull << 20));           // [32,64)  G4..p3
    unsigned short* x_bf    = (unsigned short*)(ws + (64ull << 20));  // [64,72)  prep..G1
    unsigned short* y_bf    = (unsigned short*)(ws + (64ull << 20));  // [64,80)  p3..G5
    unsigned short* Wint    = (unsigned short*)(ws + (72ull << 20));  // [72,80)  prep..G1
    unsigned short* pw_t    = (unsigned short*)(ws + (80ull << 20));  // [80,88)  prep..G2
    unsigned short* xcp_bf  = (unsigned short*)(ws + (88ull << 20));  // [88,104) conv..G2
    unsigned short* xc_bf   = (unsigned short*)(ws + (104ull << 20)); // [104,120) G2..p3
    unsigned short* Woutt   = (unsigned short*)(ws + (120ull << 20)); // [120,124) prep..G5
    float*          xdbl    = (float*)(ws + (124ull << 20));          // [124,125.4) g3red..p3
    float*          g3part  = (float*)(ws + (126ull << 20));          // [126,136) g3..g3red
    float*          cs_a    = (float*)(ws + (136ull << 20));          // [136,144) p1..p2
    float*          cs_h    = (float*)(ws + (144ull << 20));          // [144,152) p1..p3
    float*          hin     = cs_h;   // in-place
    dim3 blk(256);

    // prep: cast + 3 transposes fused into one dispatch
    prep_all<<<14336, blk, 0, stream>>>(x, W_in, pwk, W_out,
                                        x_bf, Wint, pw_t, Woutt);

    // G1: xz = x @ W_in, deinterleaved bf16 (x_in | z). NW=4, TN=128,
    // 1024 blocks = 4/CU.
    mfma_gemm<0, 4, 128, unsigned short>
        <<<dim3((2 * DINNER) / 128, MM / 128), blk, 0, stream>>>(
        x_bf, Wint, x_in_bf, z_bf, DINNER,
        MM, 2 * DINNER, DMODEL, DMODEL, DMODEL, DINNER, nullptr);

    // depthwise causal conv (bf16 in, bf16 out)
    dwconv_kernel<<<MM * DINNER / 4 / 256, blk, 0, stream>>>(x_in_bf, dwk, xcp_bf);

    // G2: xc = silu(conv @ pw + conv_bias) -> bf16. NW=8, TN=128 (r6/r9/r11
    // winner; r10's split-K + reduce net-regressed).
    mfma_gemm<1, 8, 128, unsigned short>
        <<<dim3(DINNER / 128, MM / 128), dim3(512), 0, stream>>>(
        xcp_bf, pw_t, xc_bf, xc_bf, DINNER + 1,
        MM, DINNER, DINNER, DINNER, DINNER, DINNER, conv_bias);

    // G3: x_dbl partials = xc @ W_x (split-K fp32) + materialized reduce
    g3_splitk<<<dim3(MM / 64, G3_KCH), blk, 0, stream>>>(xc_bf, W_x, g3part);
    g3_reduce<<<(MM * 80 / 4 + 255) / 256, blk, 0, stream>>>(g3part, xdbl);

    // G4: delta = softplus(xdbl[:, :64] @ W_dt + b_dt)  (fp32, xdbl L2-hot)
    gemm_tiled_sp<<<dim3(DINNER / 64, MM / 64), blk, 0, stream>>>(
        xdbl, W_dt, delta, MM, DINNER, DTRANK, 80, DINNER, DINNER, b_dt);

    // selective scan, 3-pass chunked (CL=32, NCH=64 — proven)
    scan_pass1<<<dim3(DINNER / 256, NCH, Bb), blk, 0, stream>>>(
        delta, xc_bf, xdbl, A_log, cs_a, cs_h);
    scan_pass2<<<(Bb * 8 * DINNER + 255) / 256, blk, 0, stream>>>(cs_a, cs_h, hin);
    scan_pass3<<<dim3(DINNER / 256, NCH, Bb), blk, 0, stream>>>(
        delta, xc_bf, xdbl, A_log, hin, z_bf, Dv, y_bf);

    // G5: out = y @ W_out. NW=4, TN=64 -> 512 blocks, direct write.
    mfma_gemm<0, 4, 64, float>
        <<<dim3(DMODEL / 64, MM / 128), blk, 0, stream>>>(
        y_bf, Woutt, out, out, DMODEL + 1,
        MM, DMODEL, DINNER, DINNER, DINNER, DMODEL, nullptr);
}

// Round 14
// 374.764 us; speedup vs baseline: 1.0710x; 1.0177x over previous
//
#include <hip/hip_runtime.h>
#include <math.h>

// Problem constants
#define Bb 2
#define Ll 2048
#define DMODEL 1024
#define DINNER 2048
#define DSTATE 8
#define DTRANK 64
#define DCONV 4
#define MM (Bb*Ll)          // 4096 rows
// scan chunking (CL=32 proven best: r12's CL=64 halved p1/p3 occupancy, +24us)
#define NCH 64
#define CL 32               // NCH*CL == Ll
// G3 split-K
#define G3_KCH 8
#define G3_KC (DINNER / G3_KCH)   // 256

typedef __attribute__((ext_vector_type(8))) short    bf16x8;
typedef __attribute__((ext_vector_type(4))) float    f32x4;

__device__ __forceinline__ float silu_f(float x) {
    return x / (1.0f + __expf(-x));
}
__device__ __forceinline__ float softplus_f(float x) {
    return fmaxf(x, 0.0f) + log1pf(__expf(-fabsf(x)));
}
__device__ __forceinline__ unsigned short f2bf(float f) {
    unsigned int u = __float_as_uint(f);
    u += 0x7fffu + ((u >> 16) & 1u);      // RNE
    return (unsigned short)(u >> 16);
}
__device__ __forceinline__ float bf2f(unsigned short u) {
    return __uint_as_float(((unsigned int)u) << 16);
}
// async 16B global->LDS (wave-uniform LDS base + lane*16 dest)
__device__ __forceinline__ void async_cp16(const unsigned short* g, unsigned short* l) {
    __builtin_amdgcn_global_load_lds(
        (const __attribute__((address_space(1))) void*)g,
        (__attribute__((address_space(3))) void*)l, 16, 0, 0);
}

// ---------------------------------------------------------------------------
// bf16 MFMA GEMM (r11-proven): NW waves, tile 128 x TN, BK=32, double-
// buffered async staging, flat LDS + 16B-slot XOR swizzle -> 0 bank
// conflicts. ~650-670 TF structural plateau (1-barrier K-loop, m97-class);
// measured invariant across NW/TN/split-K (r5-r11).
// EPI: 0 none, 1 silu(x+bias[n]), 2 softplus(x+bias[n]).
// ---------------------------------------------------------------------------
template <int EPI, int NW, int TN, typename OT>
__global__ __launch_bounds__(NW * 64, 4) void mfma_gemm(
    const unsigned short* __restrict__ A, const unsigned short* __restrict__ Bt,
    OT* __restrict__ C, OT* __restrict__ C2, int nsplit,
    int M, int N, int K, int lda, int ldb, int ldc,
    const float* __restrict__ bias)
{
    constexpr int NT   = NW * 64;     // threads
    constexpr int WNC  = NW / 2;      // waves along n
    constexpr int WNE  = TN / WNC;    // wave n-extent
    constexpr int NJ   = WNE / 16;    // b-frags per wave
    constexpr int RPP  = NT / 4;      // tile rows staged per pass
    constexpr int APASS = 128 / RPP;
    constexpr int BPASS = TN / RPP;

    __shared__ unsigned short As[2][128 * 32];   // 2 x 8 KB
    __shared__ unsigned short Bs[2][TN * 32];

    const int bm = blockIdx.y * 128;
    const int bn = blockIdx.x * TN;
    const int tid  = threadIdx.x;
    const int w    = tid >> 6;
    const int lane = tid & 63;
    const int wm = (w / WNC) * 64;
    const int wn = (w % WNC) * WNE;
    const int lr = lane & 15;
    const int lq = lane >> 4;

    // staging: thread t covers row t>>2 (+p*RPP per pass), 16B slot t&3.
    // Swizzle applied on the GLOBAL column; (row + p*RPP)>>1 mod 4 invariant.
    const int row  = tid >> 2;
    const int sp   = tid & 3;
    const int slog = sp ^ ((row >> 1) & 3);
    const unsigned short* gA = A  + (size_t)(bm + row) * lda + slog * 8;
    const unsigned short* gB = Bt + (size_t)(bn + row) * ldb + slog * 8;
    const int st = tid * 8;

    // fragment read offset (logical slot lq at phys slot lq^((lr>>1)&3))
    const int fsw = (lq ^ ((lr >> 1) & 3)) * 8;

    f32x4 acc[4][NJ];
#pragma unroll
    for (int i = 0; i < 4; ++i)
#pragma unroll
        for (int j = 0; j < NJ; ++j) acc[i][j] = (f32x4){0.f, 0.f, 0.f, 0.f};

    // prologue: tile 0 -> buffer 0
#pragma unroll
    for (int p = 0; p < APASS; ++p)
        async_cp16(gA + (size_t)p * RPP * lda, &As[0][p * RPP * 32 + st]);
#pragma unroll
    for (int p = 0; p < BPASS; ++p)
        async_cp16(gB + (size_t)p * RPP * ldb, &Bs[0][p * RPP * 32 + st]);

    int cur = 0;
    for (int k0 = 0; k0 < K; k0 += 32, cur ^= 1) {
        __syncthreads();   // drains tile-k loads (vmcnt) + prev ds_reads (lgkm)
        const int nk = k0 + 32;
        if (nk < K) {
            const int nb = cur ^ 1;
#pragma unroll
            for (int p = 0; p < APASS; ++p)
                async_cp16(gA + (size_t)p * RPP * lda + nk, &As[nb][p * RPP * 32 + st]);
#pragma unroll
            for (int p = 0; p < BPASS; ++p)
                async_cp16(gB + (size_t)p * RPP * ldb + nk, &Bs[nb][p * RPP * 32 + st]);
        }

        bf16x8 a[4], b[NJ];
#pragma unroll
        for (int i = 0; i < 4; ++i)
            a[i] = *(const bf16x8*)&As[cur][(wm + i * 16 + lr) * 32 + fsw];
#pragma unroll
        for (int j = 0; j < NJ; ++j)
            b[j] = *(const bf16x8*)&Bs[cur][(wn + j * 16 + lr) * 32 + fsw];
#pragma unroll
        for (int i = 0; i < 4; ++i)
#pragma unroll
            for (int j = 0; j < NJ; ++j)
                acc[i][j] = __builtin_amdgcn_mfma_f32_16x16x32_bf16(
                    a[i], b[j], acc[i][j], 0, 0, 0);
    }

    // epilogue: C/D layout col = lane&15, row = (lane>>4)*4 + reg
#pragma unroll
    for (int i = 0; i < 4; ++i) {
        const int row0 = bm + wm + i * 16 + lq * 4;
#pragma unroll
        for (int j = 0; j < NJ; ++j) {
            const int col = bn + wn + j * 16 + lr;
            OT* Cb; int colb;
            if (col < nsplit) { Cb = C; colb = col; }
            else              { Cb = C2; colb = col - nsplit; }
            float bv = (EPI != 0) ? bias[col] : 0.0f;
#pragma unroll
            for (int r = 0; r < 4; ++r) {
                float v = acc[i][j][r];
                if (EPI == 1) v = silu_f(v + bv);
                if (EPI == 2) v = softplus_f(v + bv);
                if (sizeof(OT) == 2)
                    Cb[(size_t)(row0 + r) * ldc + colb] = (OT)f2bf(v);
                else
                    Cb[(size_t)(row0 + r) * ldc + colb] = (OT)v;
            }
        }
    }
}

// ---------------------------------------------------------------------------
// prep_all: ONE kernel for input cast + 4 weight transpose-casts. Ranges:
//   [0,4096)       cast x -> bf16 (1024 elems/block)
//   [4096,8192)    W_in  [1024][4096] -> Wint  [4096][1024]
//   [8192,12288)   pwk   [2048][2048] -> pw_t  [2048][2048]
//   [12288,14336)  W_out [2048][1024] -> Woutt [1024][2048]
//   [14336,14464)  W_dt  [64][2048]   -> Wdtt  [2048][64]    (r14: G4->MFMA)
// ---------------------------------------------------------------------------
__global__ __launch_bounds__(256) void prep_all(
    const float* __restrict__ x, const float* __restrict__ W_in,
    const float* __restrict__ pwk, const float* __restrict__ W_out,
    const float* __restrict__ W_dt,
    unsigned short* __restrict__ x_bf, unsigned short* __restrict__ Wint,
    unsigned short* __restrict__ pw_t, unsigned short* __restrict__ Woutt,
    unsigned short* __restrict__ Wdtt)
{
    const int b = blockIdx.x;
    const int t = threadIdx.x;
    if (b < 4096) {                       // cast
        int i = b * 1024 + t * 4;
        float4 v = *(const float4*)&x[i];
        ushort4 o;
        o.x = f2bf(v.x); o.y = f2bf(v.y); o.z = f2bf(v.z); o.w = f2bf(v.w);
        *(ushort4*)&x_bf[i] = o;
        return;
    }
    // transpose-cast: src[R][C] -> dst[C][R], 32x32 tile
    const float* src; unsigned short* dst; int R, C, c0, r0;
    if (b < 8192) {
        int bi = b - 4096; src = W_in; dst = Wint; R = 1024; C = 4096;
        c0 = (bi & 127) * 32; r0 = (bi >> 7) * 32;
    } else if (b < 12288) {
        int bi = b - 8192; src = pwk; dst = pw_t; R = 2048; C = 2048;
        c0 = (bi & 63) * 32; r0 = (bi >> 6) * 32;
    } else if (b < 14336) {
        int bi = b - 12288; src = W_out; dst = Woutt; R = 2048; C = 1024;
        c0 = (bi & 31) * 32; r0 = (bi >> 5) * 32;
    } else {
        int bi = b - 14336; src = W_dt; dst = Wdtt; R = 64; C = 2048;
        c0 = (bi & 63) * 32; r0 = (bi >> 6) * 32;   // 64 x 2 tiles
    }
    __shared__ float tile[32][33];
    const int tx = t & 31;
    const int ty = t >> 5;                // 0..7
#pragma unroll
    for (int i = 0; i < 32; i += 8)
        tile[ty + i][tx] = src[(size_t)(r0 + ty + i) * C + c0 + tx];
    __syncthreads();
#pragma unroll
    for (int i = 0; i < 32; i += 8)
        dst[(size_t)(c0 + ty + i) * R + r0 + tx] = f2bf(tile[tx][ty + i]);
}

// ---------------------------------------------------------------------------
// G3 split-K: part[kc][M][80] = xc_bf[:, kc*256:(kc+1)*256] @ W_x-chunk
// ---------------------------------------------------------------------------
__global__ __launch_bounds__(256) void g3_splitk(
    const unsigned short* __restrict__ xc, const float* __restrict__ Wx,
    float* __restrict__ part)
{
    __shared__ float As[16][68];   // [k][row]
    __shared__ float Bs[16][85];   // [k][col]
    const int m0 = blockIdx.x * 64;
    const int kb = blockIdx.y * G3_KC;
    const int t = threadIdx.x;
    const int tr = t >> 4;
    const int tc = t & 15;

    const int arow = t >> 2;
    const int ak4  = (t & 3) * 4;
    const int bk   = t >> 4;
    const int bc   = (t & 15) * 5;

    float acc[4][5];
#pragma unroll
    for (int r = 0; r < 4; ++r)
#pragma unroll
        for (int c = 0; c < 5; ++c) acc[r][c] = 0.0f;

    for (int k0 = 0; k0 < G3_KC; k0 += 16) {
        ushort4 av = *(const ushort4*)&xc[(size_t)(m0 + arow) * DINNER + kb + k0 + ak4];
        float bv[5];
#pragma unroll
        for (int q = 0; q < 5; ++q)
            bv[q] = Wx[(size_t)(kb + k0 + bk) * 80 + bc + q];
        __syncthreads();
        As[ak4 + 0][arow] = bf2f(av.x);
        As[ak4 + 1][arow] = bf2f(av.y);
        As[ak4 + 2][arow] = bf2f(av.z);
        As[ak4 + 3][arow] = bf2f(av.w);
#pragma unroll
        for (int q = 0; q < 5; ++q) Bs[bk][bc + q] = bv[q];
        __syncthreads();
#pragma unroll
        for (int k = 0; k < 16; ++k) {
            float a[4], b[5];
#pragma unroll
            for (int r = 0; r < 4; ++r) a[r] = As[k][tr * 4 + r];
#pragma unroll
            for (int c = 0; c < 5; ++c) b[c] = Bs[k][tc * 5 + c];
#pragma unroll
            for (int r = 0; r < 4; ++r)
#pragma unroll
                for (int c = 0; c < 5; ++c)
                    acc[r][c] = fmaf(a[r], b[c], acc[r][c]);
        }
    }
#pragma unroll
    for (int r = 0; r < 4; ++r)
#pragma unroll
        for (int c = 0; c < 5; ++c)
            part[((size_t)blockIdx.y * MM + m0 + tr * 4 + r) * 80 + tc * 5 + c] = acc[r][c];
}

// reduce 8 partials -> xdbl fp32 (1.25 MB) AND bf16 copy of the delta cols
// (0..63) as dense [M][64] for the MFMA G4 (r14).
__global__ __launch_bounds__(256) void g3_reduce(
    const float* __restrict__ part, float* __restrict__ xdbl,
    unsigned short* __restrict__ xdbl64)
{
    int i = (blockIdx.x * 256 + threadIdx.x) * 4;
    if (i >= MM * 80) return;
    float4 s = *(const float4*)&part[i];
#pragma unroll
    for (int c = 1; c < G3_KCH; ++c) {
        float4 p = *(const float4*)&part[(size_t)c * MM * 80 + i];
        s.x += p.x; s.y += p.y; s.z += p.z; s.w += p.w;
    }
    *(float4*)&xdbl[i] = s;
    int col = i % 80;
    if (col < 64) {
        int row = i / 80;
        ushort4 o;
        o.x = f2bf(s.x); o.y = f2bf(s.y); o.z = f2bf(s.z); o.w = f2bf(s.w);
        *(ushort4*)&xdbl64[(size_t)row * 64 + col] = o;
    }
}

// ---------------------------------------------------------------------------
// Depthwise causal conv on dense bf16 x_in [M][DINNER]; bf16 out; x4 vector.
// ---------------------------------------------------------------------------
__global__ __launch_bounds__(256) void dwconv_kernel(
    const unsigned short* __restrict__ x_in, const float* __restrict__ dwk,
    unsigned short* __restrict__ out)
{
    int i4 = blockIdx.x * 256 + threadIdx.x;
    if (i4 >= MM * DINNER / 4) return;
    int d = (i4 * 4) & (DINNER - 1);
    int bl = (i4 * 4) >> 11;
    int l = bl & (Ll - 1);
    int b = bl >> 11;
    float a0 = 0.f, a1 = 0.f, a2 = 0.f, a3 = 0.f;
#pragma unroll
    for (int k = 0; k < DCONV; ++k) {
        int t = l + k - (DCONV - 1);
        if (t >= 0) {
            ushort4 xv = *(const ushort4*)&x_in[(size_t)(b * Ll + t) * DINNER + d];
            float4 wv = *(const float4*)&dwk[k * DINNER + d];
            a0 = fmaf(bf2f(xv.x), wv.x, a0);
            a1 = fmaf(bf2f(xv.y), wv.y, a1);
            a2 = fmaf(bf2f(xv.z), wv.z, a2);
            a3 = fmaf(bf2f(xv.w), wv.w, a3);
        }
    }
    ushort4 o;
    o.x = f2bf(a0); o.y = f2bf(a1); o.z = f2bf(a2); o.w = f2bf(a3);
    *(ushort4*)&out[i4 * 4] = o;
}

// ---------------------------------------------------------------------------
// Selective scan pass 1: per-chunk local scan from h=0. xc is bf16.
// sB from xdbl (materialized reduce).
// ---------------------------------------------------------------------------
__global__ __launch_bounds__(256) void scan_pass1(
    const float* __restrict__ delta, const unsigned short* __restrict__ xc,
    const float* __restrict__ xdbl, const float* __restrict__ A_log,
    float* __restrict__ cs_a, float* __restrict__ cs_h)
{
    const int d = blockIdx.x * 256 + threadIdx.x;
    const int c = blockIdx.y;
    const int b = blockIdx.z;
    const int t0 = c * CL;

    __shared__ float sB[CL][8];
    {
        int i = threadIdx.x;
        int t = i >> 3, j = i & 7;
        sB[t][j] = xdbl[((size_t)(b * Ll + t0 + t)) * 80 + DTRANK + j];
    }
    __syncthreads();

    float An[8];
#pragma unroll
    for (int n = 0; n < 8; ++n) An[n] = -__expf(A_log[d * 8 + n]);

    float h[8], ap[8];
#pragma unroll
    for (int n = 0; n < 8; ++n) { h[n] = 0.0f; ap[n] = 1.0f; }

    const float* dptr = delta + ((size_t)(b * Ll + t0)) * DINNER + d;
    const unsigned short* xptr = xc + ((size_t)(b * Ll + t0)) * DINNER + d;

#pragma unroll 4
    for (int t = 0; t < CL; ++t) {
        float dl = dptr[(size_t)t * DINNER];
        float xv = bf2f(xptr[(size_t)t * DINNER]);
        float du = dl * xv;
#pragma unroll
        for (int n = 0; n < 8; ++n) {
            float dA = __expf(dl * An[n]);
            h[n] = fmaf(dA, h[n], du * sB[t][n]);
            ap[n] *= dA;
        }
    }

    size_t base = (((size_t)(b * NCH + c)) * 8) * DINNER + d;
#pragma unroll
    for (int n = 0; n < 8; ++n) {
        cs_a[base + (size_t)n * DINNER] = ap[n];
        cs_h[base + (size_t)n * DINNER] = h[n];
    }
}

// Pass 2: sequential combine; hin ALIASES cs_h (in-place) — read-before-write.
__global__ __launch_bounds__(256) void scan_pass2(
    const float* __restrict__ cs_a, const float* cs_h, float* hin)
{
    int idx = blockIdx.x * 256 + threadIdx.x;
    if (idx >= Bb * 8 * DINNER) return;
    int d = idx & (DINNER - 1);
    int n = (idx >> 11) & 7;
    int b = idx >> 14;
    float H = 0.0f;
#pragma unroll 4
    for (int c = 0; c < NCH; ++c) {
        size_t o = (((size_t)(b * NCH + c)) * 8 + n) * DINNER + d;
        float a = cs_a[o];
        float hh = cs_h[o];
        hin[o] = H;
        H = fmaf(a, H, hh);
    }
}

// Pass 3: replay with correct h_in; fused epilogue -> bf16 y. z dense bf16.
// sB/sC from xdbl.
__global__ __launch_bounds__(256) void scan_pass3(
    const float* __restrict__ delta, const unsigned short* __restrict__ xc,
    const float* __restrict__ xdbl, const float* __restrict__ A_log,
    const float* __restrict__ hin, const unsigned short* __restrict__ z,
    const float* __restrict__ Dvec, unsigned short* __restrict__ y_bf)
{
    const int d = blockIdx.x * 256 + threadIdx.x;
    const int c = blockIdx.y;
    const int b = blockIdx.z;
    const int t0 = c * CL;

    __shared__ float sB[CL][8];
    __shared__ float sC[CL][8];
    {
        int i = threadIdx.x;
        int t = i >> 4, j = i & 15;
        float v = xdbl[((size_t)(b * Ll + t0 + t)) * 80 + DTRANK + j];
        if (j < 8) sB[t][j] = v; else sC[t][j - 8] = v;
        t = (i + 256) >> 4; j = (i + 256) & 15;
        v = xdbl[((size_t)(b * Ll + t0 + t)) * 80 + DTRANK + j];
        if (j < 8) sB[t][j] = v; else sC[t][j - 8] = v;
    }
    __syncthreads();

    float An[8];
#pragma unroll
    for (int n = 0; n < 8; ++n) An[n] = -__expf(A_log[d * 8 + n]);

    float h[8];
    size_t hbase = (((size_t)(b * NCH + c)) * 8) * DINNER + d;
#pragma unroll
    for (int n = 0; n < 8; ++n) h[n] = hin[hbase + (size_t)n * DINNER];

    const float Dd = Dvec[d];
    const float* dptr = delta + ((size_t)(b * Ll + t0)) * DINNER + d;
    const unsigned short* xptr = xc + ((size_t)(b * Ll + t0)) * DINNER + d;
    const unsigned short* zptr = z + ((size_t)(b * Ll + t0)) * DINNER + d;
    unsigned short* yptr = y_bf + ((size_t)(b * Ll + t0)) * DINNER + d;

    for (int t = 0; t < CL; ++t) {
        float dl = dptr[(size_t)t * DINNER];
        float xv = bf2f(xptr[(size_t)t * DINNER]);
        float du = dl * xv;
        float yt = 0.0f;
#pragma unroll
        for (int n = 0; n < 8; ++n) {
            float dA = __expf(dl * An[n]);
            h[n] = fmaf(dA, h[n], du * sB[t][n]);
            yt = fmaf(sC[t][n], h[n], yt);
        }
        float zv = bf2f(zptr[(size_t)t * DINNER]);
        yptr[(size_t)t * DINNER] = f2bf((yt + xv * Dd) * silu_f(zv));
    }
}

// ---------------------------------------------------------------------------
extern "C" void kernel_launch(void* const* d_in, const int* in_sizes, int n_in,
                              void* d_out, int out_size, void* d_ws, size_t ws_size,
                              hipStream_t stream)
{
    const float* x         = (const float*)d_in[0];
    const float* W_in      = (const float*)d_in[1];
    const float* dwk       = (const float*)d_in[2];
    const float* pwk       = (const float*)d_in[3];
    const float* conv_bias = (const float*)d_in[4];
    const float* W_x       = (const float*)d_in[5];
    const float* W_dt      = (const float*)d_in[6];
    const float* b_dt      = (const float*)d_in[7];
    const float* A_log     = (const float*)d_in[8];
    const float* Dv        = (const float*)d_in[9];
    const float* W_out     = (const float*)d_in[10];
    float* out = (float*)d_out;

    // workspace map (MiB offsets; peak 152.25 MiB <= proven 154)
    char* ws = (char*)d_ws;
    unsigned short* x_in_bf = (unsigned short*)(ws);                  // [0,16)   G1..conv
    unsigned short* z_bf    = (unsigned short*)(ws + (16ull << 20));  // [16,32)  G1..p3
    float*          delta   = (float*)(ws + (32ull << 20));           // [32,64)  G4..p3
    unsigned short* x_bf    = (unsigned short*)(ws + (64ull << 20));  // [64,72)  prep..G1
    unsigned short* y_bf    = (unsigned short*)(ws + (64ull << 20));  // [64,80)  p3..G5
    unsigned short* Wint    = (unsigned short*)(ws + (72ull << 20));  // [72,80)  prep..G1
    unsigned short* pw_t    = (unsigned short*)(ws + (80ull << 20));  // [80,88)  prep..G2
    unsigned short* xcp_bf  = (unsigned short*)(ws + (88ull << 20));  // [88,104) conv..G2
    unsigned short* xc_bf   = (unsigned short*)(ws + (104ull << 20)); // [104,120) G2..p3
    unsigned short* Woutt   = (unsigned short*)(ws + (120ull << 20)); // [120,124) prep..G5
    float*          xdbl    = (float*)(ws + (124ull << 20));          // [124,125.25) g3red..p3
    unsigned short* xdbl64  = (unsigned short*)(ws + (125ull << 20) + (512ull << 10)); // 0.5 MB, g3red..G4
    float*          g3part  = (float*)(ws + (126ull << 20));          // [126,136) g3..g3red
    float*          cs_a    = (float*)(ws + (136ull << 20));          // [136,144) p1..p2
    float*          cs_h    = (float*)(ws + (144ull << 20));          // [144,152) p1..p3
    unsigned short* Wdtt    = (unsigned short*)(ws + (152ull << 20)); // 0.25 MB, prep..G4
    float*          hin     = cs_h;   // in-place
    dim3 blk(256);

    // prep: cast + 4 transposes fused into one dispatch
    prep_all<<<14464, blk, 0, stream>>>(x, W_in, pwk, W_out, W_dt,
                                        x_bf, Wint, pw_t, Woutt, Wdtt);

    // G1: xz = x @ W_in, deinterleaved bf16 (x_in | z). NW=4, TN=128,
    // 1024 blocks = 4/CU.
    mfma_gemm<0, 4, 128, unsigned short>
        <<<dim3((2 * DINNER) / 128, MM / 128), blk, 0, stream>>>(
        x_bf, Wint, x_in_bf, z_bf, DINNER,
        MM, 2 * DINNER, DMODEL, DMODEL, DMODEL, DINNER, nullptr);

    // depthwise causal conv (bf16 in, bf16 out)
    dwconv_kernel<<<MM * DINNER / 4 / 256, blk, 0, stream>>>(x_in_bf, dwk, xcp_bf);

    // G2: xc = silu(conv @ pw + conv_bias) -> bf16. NW=8, TN=128 (winner).
    mfma_gemm<1, 8, 128, unsigned short>
        <<<dim3(DINNER / 128, MM / 128), dim3(512), 0, stream>>>(
        xcp_bf, pw_t, xc_bf, xc_bf, DINNER + 1,
        MM, DINNER, DINNER, DINNER, DINNER, DINNER, conv_bias);

    // G3: x_dbl partials = xc @ W_x (split-K fp32) + materialized reduce
    // (emits fp32 xdbl for scan B/C + bf16 xdbl64 for MFMA G4)
    g3_splitk<<<dim3(MM / 64, G3_KCH), blk, 0, stream>>>(xc_bf, W_x, g3part);
    g3_reduce<<<(MM * 80 / 4 + 255) / 256, blk, 0, stream>>>(g3part, xdbl, xdbl64);

    // G4: delta = softplus(xdbl64 @ Wdtt^T + b_dt) — MFMA, K=64 (2 iters).
    // bf16 matmul is safe here: pre-activation std ~0.002 vs delta ~0.69,
    // so bf16 input rounding perturbs delta by ~1e-5 abs -> dA by ~0.01%.
    mfma_gemm<2, 4, 128, float>
        <<<dim3(DINNER / 128, MM / 128), blk, 0, stream>>>(
        xdbl64, Wdtt, delta, delta, DINNER + 1,
        MM, DINNER, DTRANK, DTRANK, DTRANK, DINNER, b_dt);

    // selective scan, 3-pass chunked (CL=32, NCH=64 — proven)
    scan_pass1<<<dim3(DINNER / 256, NCH, Bb), blk, 0, stream>>>(
        delta, xc_bf, xdbl, A_log, cs_a, cs_h);
    scan_pass2<<<(Bb * 8 * DINNER + 255) / 256, blk, 0, stream>>>(cs_a, cs_h, hin);
    scan_pass3<<<dim3(DINNER / 256, NCH, Bb), blk, 0, stream>>>(
        delta, xc_bf, xdbl, A_log, hin, z_bf, Dv, y_bf);

    // G5: out = y @ W_out. NW=4, TN=64 -> 512 blocks, direct write.
    mfma_gemm<0, 4, 64, float>
        <<<dim3(DMODEL / 64, MM / 128), blk, 0, stream>>>(
        y_bf, Woutt, out, out, DMODEL + 1,
        MM, DMODEL, DINNER, DINNER, DINNER, DMODEL, nullptr);
}